// Round 1
// baseline (1483.354 us; speedup 1.0000x reference)
//
#include <hip/hip_runtime.h>
#include <hip/hip_bf16.h>

// Problem constants
#define BB 32768
#define EE 90
#define HH 32
#define NEG_SLOPE 0.33f

typedef __bf16 bf16x8 __attribute__((ext_vector_type(8)));
typedef float  f32x4  __attribute__((ext_vector_type(4)));

__device__ __forceinline__ float leaky(float x) {
    return x >= 0.0f ? x : NEG_SLOPE * x;
}

// Load one MFMA A/B fragment row slice: 8 consecutive k-values starting at kq
// (kq = c*32 + quad*8), converted fp32 -> bf16. TAIL=true predicates k >= 90
// to zero (avoids OOB reads past the array AND NaN*0 poisoning).
// All addresses are 8B-aligned (every index component is even), so float2 is safe.
template <bool TAIL>
__device__ __forceinline__ bf16x8 load_frag(const float* __restrict__ p, int kq) {
    bf16x8 r;
#pragma unroll
    for (int j = 0; j < 8; j += 2) {
        float2 v;
        if (!TAIL || (kq + j) < EE) {
            v = *(const float2*)(p + kq + j);
        } else {
            v = make_float2(0.0f, 0.0f);
        }
        r[j]     = (__bf16)v.x;
        r[j + 1] = (__bf16)v.y;
    }
    return r;
}

// Grid: 128 b-blocks (256 b each) x 6 e-groups (15 e each) = 768 blocks.
// Block: 256 threads = 4 waves; wave w handles b-subtile of 64 (4 m-tiles of 16).
// No LDS, no __syncthreads: fragments are loaded per-lane straight from global.
__global__ __launch_bounds__(256, 4)
void nolinersem_kernel(const float* __restrict__ x,   // (B,1,E,E)
                       const float* __restrict__ W1,  // (E,H,E)
                       const float* __restrict__ b1,  // (E,H)
                       const float* __restrict__ W2,  // (E,1,H)
                       const float* __restrict__ b2,  // (E,1)
                       float* __restrict__ out) {     // (B,E)
    const int lane = threadIdx.x & 63;
    const int l15  = lane & 15;   // MFMA: A row (b) / B col (h) / D col (h)
    const int q    = lane >> 4;   // MFMA quad: k-chunk (input), row-group (output)
    const int wave = threadIdx.x >> 6;

    const int bblk = blockIdx.x & 127;  // 0..127  -> 256 b's each
    const int eg   = blockIdx.x >> 7;   // 0..5    -> 15 e's each

    const int b0 = bblk * 256 + wave * 64;  // this wave's 64 b's
    const int e_begin = eg * 15;
    const int e_end   = e_begin + 15;

    // Per-m-tile x row base pointers (row = b0 + mt*16 + l15), stride 8100 floats.
    const float* xr[4];
#pragma unroll
    for (int mt = 0; mt < 4; ++mt)
        xr[mt] = x + (size_t)(b0 + mt * 16 + l15) * (EE * EE);

    // W1 fragment rows: h = l15 (n-tile 0) and h = l15+16 (n-tile 1), stride 90.
    const float* w1r0 = W1 + (size_t)l15 * EE;
    const float* w1r1 = W1 + (size_t)(l15 + 16) * EE;

    for (int e = e_begin; e < e_end; ++e) {
        const int xoff  = e * EE;            // offset into each x row block
        const float* w1e0 = w1r0 + (size_t)e * (HH * EE);
        const float* w1e1 = w1r1 + (size_t)e * (HH * EE);

        f32x4 acc[4][2];
#pragma unroll
        for (int mt = 0; mt < 4; ++mt)
#pragma unroll
            for (int nt = 0; nt < 2; ++nt)
                acc[mt][nt] = (f32x4){0.0f, 0.0f, 0.0f, 0.0f};

        // K loop: 90 padded to 96 = 3 chunks of 32. Chunk 2 is the tail.
#pragma unroll
        for (int c = 0; c < 3; ++c) {
            const int kq = c * 32 + q * 8;
            bf16x8 bf0, bf1;
            if (c < 2) {
                bf0 = load_frag<false>(w1e0, kq);
                bf1 = load_frag<false>(w1e1, kq);
            } else {
                bf0 = load_frag<true>(w1e0, kq);
                bf1 = load_frag<true>(w1e1, kq);
            }
#pragma unroll
            for (int mt = 0; mt < 4; ++mt) {
                bf16x8 af;
                if (c < 2) af = load_frag<false>(xr[mt] + xoff, kq);
                else       af = load_frag<true >(xr[mt] + xoff, kq);
                acc[mt][0] = __builtin_amdgcn_mfma_f32_16x16x32_bf16(af, bf0, acc[mt][0], 0, 0, 0);
                acc[mt][1] = __builtin_amdgcn_mfma_f32_16x16x32_bf16(af, bf1, acc[mt][1], 0, 0, 0);
            }
        }

        // Epilogue (fp32): h = leaky(acc + b1); o = leaky(sum_h h*W2 + b2).
        // D layout: col(h) = l15 (+16 for nt=1), row(b_local) = q*4 + reg.
        const float hb0 = b1[e * HH + l15];
        const float hb1 = b1[e * HH + 16 + l15];
        const float w20 = W2[e * HH + l15];
        const float w21 = W2[e * HH + 16 + l15];
        const float b2s = b2[e];

#pragma unroll
        for (int mt = 0; mt < 4; ++mt) {
            float vr[4];
#pragma unroll
            for (int r = 0; r < 4; ++r) {
                float v = leaky(acc[mt][0][r] + hb0) * w20
                        + leaky(acc[mt][1][r] + hb1) * w21;
                // sum over the 16 h-columns held by this row-group's 16 lanes
                v += __shfl_xor(v, 1, 16);
                v += __shfl_xor(v, 2, 16);
                v += __shfl_xor(v, 4, 16);
                v += __shfl_xor(v, 8, 16);
                vr[r] = leaky(v + b2s);
            }
            // lanes with l15 < 4 store reg r = l15 for row q*4 + l15
            float vout = (l15 == 0) ? vr[0] : (l15 == 1) ? vr[1] : (l15 == 2) ? vr[2] : vr[3];
            if (l15 < 4) {
                const int b = b0 + mt * 16 + q * 4 + l15;
                out[(size_t)b * EE + e] = vout;
            }
        }
    }
}

extern "C" void kernel_launch(void* const* d_in, const int* in_sizes, int n_in,
                              void* d_out, int out_size, void* d_ws, size_t ws_size,
                              hipStream_t stream) {
    const float* x  = (const float*)d_in[0];
    const float* W1 = (const float*)d_in[1];
    const float* b1 = (const float*)d_in[2];
    const float* W2 = (const float*)d_in[3];
    const float* b2 = (const float*)d_in[4];
    float* out = (float*)d_out;

    dim3 grid(128 * 6);   // 128 b-blocks x 6 e-groups
    dim3 block(256);
    nolinersem_kernel<<<grid, block, 0, stream>>>(x, W1, b1, W2, b2, out);
}